// Round 9
// baseline (362.459 us; speedup 1.0000x reference)
//
#include <hip/hip_runtime.h>

#define VOCAB 40
#define SEQ 128
#define THREADS 256
#define ROWS_PB 32   // 8 lanes per row, 32 rows per 256-thread block
#define NW 10        // byte-packed histogram words per thread (40 bins)
#define PASSES 8     // DIAGNOSTIC: repeat full phase sequence in-kernel

// DIAGNOSTIC ROUND: the fast kernels (<77us) never surface in rocprof top-5,
// so this round loops the ENTIRE pipeline (zero -> histogram -> merge ->
// store) PASSES times in-kernel. Each pass is self-contained and idempotent
// (re-zeroed byte counters, same output values), all LDS columns are
// thread-private (no inter-thread races), and the opaque pointer asm forces
// genuine global reloads each pass (no CSE/DCE). Per-pass time = dur/PASSES.

__global__ __launch_bounds__(THREADS) void char_dist_kernel(
    const int* __restrict__ x, float* __restrict__ out, int batch) {
  __shared__ unsigned int hist[NW * THREADS];
  const int tid = threadIdx.x;
  const int l = tid & 7;
  const int row = blockIdx.x * ROWS_PB + (tid >> 3);
  const bool active = row < batch;

  unsigned int* hb = &hist[tid];  // this thread's column, stride 256 words
  const int4* gp0 = reinterpret_cast<const int4*>(x) + ((long)row << 5) + l;

#pragma unroll 1
  for (int p = 0; p < PASSES; ++p) {
    const int4* gp = gp0;
    asm volatile("" : "+v"(gp));  // opaque: force real reloads every pass

#pragma unroll
    for (int w = 0; w < NW; ++w) hb[w * THREADS] = 0u;
    __builtin_amdgcn_wave_barrier();

    if (active) {
      const int4 t0 = gp[0];
      const int4 t1 = gp[8];
      const int4 t2 = gp[16];
      const int4 t3 = gp[24];
#define HADD(t) hb[(((unsigned)(t)) >> 2) * THREADS] += 1u << (((t) & 3) << 3);
      HADD(t0.x) HADD(t0.y) HADD(t0.z) HADD(t0.w)
      HADD(t1.x) HADD(t1.y) HADD(t1.z) HADD(t1.w)
      HADD(t2.x) HADD(t2.y) HADD(t2.z) HADD(t2.w)
      HADD(t3.x) HADD(t3.y) HADD(t3.z) HADD(t3.w)
    }
    __builtin_amdgcn_wave_barrier();

    // Merge the row-group's 8 partial histograms (own column + shfl, no LDS
    // cross-thread reads, barrier-free).
    unsigned int m[NW];
#pragma unroll
    for (int w = 0; w < NW; ++w) {
      unsigned int v = hb[w * THREADS];
      v += __shfl_xor(v, 1);
      v += __shfl_xor(v, 2);
      v += __shfl_xor(v, 4);
      m[w] = v;
    }

    // Epilogue: all 8 lanes compute redundantly; lane 0 stores.
    int total = 0, uniq = 0, maxc = 0, minc = 0x7fffffff;
    int letters = 0, digits = 0, special = 0;
#pragma unroll
    for (int w = 0; w < NW; ++w) {
      const unsigned int mm = m[w];
#pragma unroll
      for (int b = 0; b < 4; ++b) {
        const int bin = w * 4 + b;
        const int c = (int)((mm >> (b * 8)) & 0xFFu);
        if (bin != 0) {  // bin 0 is padding, excluded from all stats
          total += c;
          uniq += (c > 0) ? 1 : 0;
          maxc = max(maxc, c);
          if (c > 0) minc = min(minc, c);
          if (bin <= 26) letters += c;
          else if (bin <= 36) digits += c;
          else special += c;
        }
      }
    }

    if (active && l == 0) {
      float f0, f1, f2, f3, f4, f5;
      if (total > 0) {
        const float inv = 1.0f / (float)total;
        f0 = (float)uniq * (1.0f / (float)VOCAB);
        f1 = (float)maxc * inv;
        f2 = (float)minc * inv;
        f3 = (float)letters * inv;
        f4 = (float)digits * inv;
        f5 = (float)special * inv;
      } else {
        f0 = f1 = f2 = f3 = f4 = f5 = 0.0f;
      }
      float2* o = reinterpret_cast<float2*>(out + (long)row * 6);
      o[0] = make_float2(f0, f1);
      o[1] = make_float2(f2, f3);
      o[2] = make_float2(f4, f5);
    }
    __builtin_amdgcn_wave_barrier();
  }
}

extern "C" void kernel_launch(void* const* d_in, const int* in_sizes, int n_in,
                              void* d_out, int out_size, void* d_ws, size_t ws_size,
                              hipStream_t stream) {
  const int* x = (const int*)d_in[0];
  float* out = (float*)d_out;
  const int batch = in_sizes[0] / SEQ;
  const int blocks = (batch + ROWS_PB - 1) / ROWS_PB;
  char_dist_kernel<<<blocks, THREADS, 0, stream>>>(x, out, batch);
}

// Round 11
// 248.387 us; speedup vs baseline: 1.4592x; 1.4592x over previous
//
#include <hip/hip_runtime.h>

#define VOCAB 40
#define SEQ 128
#define THREADS 256
#define ROWS_PB 32   // 8 lanes per row, 32 rows per 256-thread block
#define NW 10        // byte-packed histogram words per thread (40 bins)
#define PASSES 8     // DIAGNOSTIC: repeat full phase sequence in-kernel

// Per-pass pipeline (idempotent; opaque pointer forces real reloads):
//   zero own col-major LDS column (bank = tid%32 always, conflict-free)
//   16 tokens -> ds_add_u32 atomics (fire-and-forget, no RMW chain)
//   distributed merge: lane l sums word l across the group's 8 columns
//     (rotated column order -> 2 lanes/bank, free), partial stats on <=8 bins
//   12-shuffle packed reduce; lane 0 stores.

__global__ __launch_bounds__(THREADS) void char_dist_kernel(
    const int* __restrict__ x, float* __restrict__ out, int batch) {
  __shared__ unsigned int hist[NW * THREADS];
  const int tid = threadIdx.x;
  const int l = tid & 7;        // lane within row group
  const int gb = tid & ~7;      // group's base column
  const int row = blockIdx.x * ROWS_PB + (tid >> 3);
  const bool active = row < batch;

  unsigned int* hb = &hist[tid];  // this thread's column, stride 256 words
  const int4* gp0 = reinterpret_cast<const int4*>(x) + ((long)row << 5) + l;

#pragma unroll 1
  for (int p = 0; p < PASSES; ++p) {
    const int4* gp = gp0;
    asm volatile("" : "+v"(gp));  // opaque: force real reloads every pass

#pragma unroll
    for (int w = 0; w < NW; ++w) hb[w * THREADS] = 0u;
    __builtin_amdgcn_wave_barrier();

    if (active) {
      const int4 t0 = gp[0];
      const int4 t1 = gp[8];
      const int4 t2 = gp[16];
      const int4 t3 = gp[24];
#define HADD(t)                                                              \
  atomicAdd(&hb[(((unsigned)(t)) >> 2) * THREADS], 1u << (((t) & 3) << 3));
      HADD(t0.x) HADD(t0.y) HADD(t0.z) HADD(t0.w)
      HADD(t1.x) HADD(t1.y) HADD(t1.z) HADD(t1.w)
      HADD(t2.x) HADD(t2.y) HADD(t2.z) HADD(t2.w)
      HADD(t3.x) HADD(t3.y) HADD(t3.z) HADD(t3.w)
    }
    // Same-wave visibility (group is sub-wave; DS ops in-order per wave).
    __builtin_amdgcn_wave_barrier();

    int total = 0, uniq = 0, maxc = 0, minc = 0x7fffffff;
    int letters = 0, digits = 0;

    // word w = l : bins 4l .. 4l+3
    {
      unsigned int m = 0;
#pragma unroll
      for (int j = 0; j < 8; ++j)
        m += hist[l * THREADS + gb + ((j + l) & 7)];
      const int bin0 = l * 4;
#pragma unroll
      for (int b = 0; b < 4; ++b) {
        const int bin = bin0 + b;
        int c = (int)((m >> (b * 8)) & 0xFFu);
        c = (bin == 0) ? 0 : c;  // bin 0 = padding, excluded from all stats
        total += c;
        uniq += (c > 0) ? 1 : 0;
        maxc = max(maxc, c);
        minc = (c > 0) ? min(minc, c) : minc;
        letters += (bin <= 26) ? c : 0;
        digits += (bin >= 27 && bin <= 36) ? c : 0;
      }
    }
    // word w = l+8 (lanes 0,1 only): bins 32..39
    if (l < 2) {
      const int w = l + 8;
      unsigned int m = 0;
#pragma unroll
      for (int j = 0; j < 8; ++j)
        m += hist[w * THREADS + gb + ((j + l) & 7)];
      const int bin0 = w * 4;
#pragma unroll
      for (int b = 0; b < 4; ++b) {
        const int bin = bin0 + b;
        const int c = (int)((m >> (b * 8)) & 0xFFu);
        total += c;
        uniq += (c > 0) ? 1 : 0;
        maxc = max(maxc, c);
        minc = (c > 0) ? min(minc, c) : minc;
        digits += (bin <= 36) ? c : 0;  // 32..36 digits; 37..39 special
      }
    }

    // Reduce across the 8 lanes: 4 quantities x 3 levels.
    unsigned int S = (unsigned)total | ((unsigned)letters << 10) |
                     ((unsigned)digits << 20);
#pragma unroll
    for (int d = 1; d < 8; d <<= 1) {
      S += __shfl_xor(S, d);
      uniq += __shfl_xor(uniq, d);
      maxc = max(maxc, __shfl_xor(maxc, d));
      minc = min(minc, __shfl_xor(minc, d));
    }

    if (active && l == 0) {
      const int totalR = (int)(S & 0x3FFu);
      const int lettersR = (int)((S >> 10) & 0x3FFu);
      const int digitsR = (int)((S >> 20) & 0x3FFu);
      const int specialR = totalR - lettersR - digitsR;
      float f0, f1, f2, f3, f4, f5;
      if (totalR > 0) {
        const float inv = 1.0f / (float)totalR;
        f0 = (float)uniq * (1.0f / (float)VOCAB);
        f1 = (float)maxc * inv;
        f2 = (float)minc * inv;
        f3 = (float)lettersR * inv;
        f4 = (float)digitsR * inv;
        f5 = (float)specialR * inv;
      } else {
        f0 = f1 = f2 = f3 = f4 = f5 = 0.0f;
      }
      float2* o = reinterpret_cast<float2*>(out + (long)row * 6);
      o[0] = make_float2(f0, f1);
      o[1] = make_float2(f2, f3);
      o[2] = make_float2(f4, f5);
    }
    __builtin_amdgcn_wave_barrier();
  }
}

extern "C" void kernel_launch(void* const* d_in, const int* in_sizes, int n_in,
                              void* d_out, int out_size, void* d_ws, size_t ws_size,
                              hipStream_t stream) {
  const int* x = (const int*)d_in[0];
  float* out = (float*)d_out;
  const int batch = in_sizes[0] / SEQ;
  const int blocks = (batch + ROWS_PB - 1) / ROWS_PB;
  char_dist_kernel<<<blocks, THREADS, 0, stream>>>(x, out, batch);
}

// Round 12
// 185.967 us; speedup vs baseline: 1.9491x; 1.3357x over previous
//
#include <hip/hip_runtime.h>

#define VOCAB 40
#define SEQ 128
#define THREADS 256
#define ROWS_PB 32   // 8 lanes per row, 32 rows per 256-thread block
#define GSTRIDE 41   // 40 bins + 1 pad word; 41 mod 32 = 9 spreads group bases

// Group-shared full-word histogram: one 40-word hist per 8-lane row group
// (all 8 lanes of a group are in the same wave -> wave_barrier-only sync).
// Per token: 1 VALU (addr lshl_add) + 1 ds_add atomic with constant data.
// No merge phase; lane l owns bins 5l..5l+4 directly. total/letters/digits/
// uniq packed in one reduce word (fields can't overflow: each <=128, uniq<=40).

__global__ __launch_bounds__(THREADS) void char_dist_kernel(
    const int* __restrict__ x, float* __restrict__ out, int batch) {
  __shared__ unsigned int hist[ROWS_PB * GSTRIDE];
  const int tid = threadIdx.x;
  const int l = tid & 7;        // lane within row group
  const int g = tid >> 3;       // row group within block
  const int row = blockIdx.x * ROWS_PB + g;
  const bool active = row < batch;

  unsigned int* gh = &hist[g * GSTRIDE];
  const int b0 = 5 * l;         // this lane's first owned bin
#pragma unroll
  for (int j = 0; j < 5; ++j) gh[b0 + j] = 0u;
  __builtin_amdgcn_wave_barrier();

  if (active) {
    const int4* gp = reinterpret_cast<const int4*>(x) + ((long)row << 5) + l;
    const int4 t0 = gp[0];
    const int4 t1 = gp[8];
    const int4 t2 = gp[16];
    const int4 t3 = gp[24];
#define HADD(t) atomicAdd(&gh[(t)], 1u);
    HADD(t0.x) HADD(t0.y) HADD(t0.z) HADD(t0.w)
    HADD(t1.x) HADD(t1.y) HADD(t1.z) HADD(t1.w)
    HADD(t2.x) HADD(t2.y) HADD(t2.z) HADD(t2.w)
    HADD(t3.x) HADD(t3.y) HADD(t3.z) HADD(t3.w)
  }
  __builtin_amdgcn_wave_barrier();

  // Lane l extracts stats from its 5 bins (full words, no unpack).
  int c0 = (int)gh[b0 + 0];
  int c1 = (int)gh[b0 + 1];
  int c2 = (int)gh[b0 + 2];
  int c3 = (int)gh[b0 + 3];
  int c4 = (int)gh[b0 + 4];
  if (l == 0) c0 = 0;  // bin 0 = padding, excluded from all stats

  int total = 0, uniq = 0, maxc = 0, minc = 255, letters = 0, digits = 0;
#define STAT(j, cc)                                                          \
  {                                                                          \
    const int bin = b0 + (j);                                                \
    total += (cc);                                                           \
    uniq += ((cc) > 0) ? 1 : 0;                                              \
    maxc = max(maxc, (cc));                                                  \
    minc = min(minc, ((cc) > 0) ? (cc) : 255);                               \
    letters += (bin <= 26) ? (cc) : 0;                                       \
    digits += (bin >= 27 && bin <= 36) ? (cc) : 0;                           \
  }
  STAT(0, c0) STAT(1, c1) STAT(2, c2) STAT(3, c3) STAT(4, c4)
#undef STAT

  // Reduce across the 8 lanes: 3 quantities x 3 levels = 9 shuffles.
  unsigned int S = (unsigned)total | ((unsigned)letters << 8) |
                   ((unsigned)digits << 16) | ((unsigned)uniq << 24);
#pragma unroll
  for (int d = 1; d < 8; d <<= 1) {
    S += __shfl_xor(S, d);
    maxc = max(maxc, __shfl_xor(maxc, d));
    minc = min(minc, __shfl_xor(minc, d));
  }

  if (active && l == 0) {
    const int totalR = (int)(S & 0xFFu);
    const int lettersR = (int)((S >> 8) & 0xFFu);
    const int digitsR = (int)((S >> 16) & 0xFFu);
    const int uniqR = (int)(S >> 24);
    const int specialR = totalR - lettersR - digitsR;
    float f0, f1, f2, f3, f4, f5;
    if (totalR > 0) {
      const float inv = 1.0f / (float)totalR;
      f0 = (float)uniqR * (1.0f / (float)VOCAB);
      f1 = (float)maxc * inv;
      f2 = (float)minc * inv;
      f3 = (float)lettersR * inv;
      f4 = (float)digitsR * inv;
      f5 = (float)specialR * inv;
    } else {
      f0 = f1 = f2 = f3 = f4 = f5 = 0.0f;
    }
    float2* o = reinterpret_cast<float2*>(out + (long)row * 6);
    o[0] = make_float2(f0, f1);
    o[1] = make_float2(f2, f3);
    o[2] = make_float2(f4, f5);
  }
}

extern "C" void kernel_launch(void* const* d_in, const int* in_sizes, int n_in,
                              void* d_out, int out_size, void* d_ws, size_t ws_size,
                              hipStream_t stream) {
  const int* x = (const int*)d_in[0];
  float* out = (float*)d_out;
  const int batch = in_sizes[0] / SEQ;
  const int blocks = (batch + ROWS_PB - 1) / ROWS_PB;
  char_dist_kernel<<<blocks, THREADS, 0, stream>>>(x, out, batch);
}